// Round 12
// baseline (171.945 us; speedup 1.0000x reference)
//
#include <hip/hip_runtime.h>
#include <math.h>

#define N_NODES 50000
#define N_EDGES 800000
#define E_TOT   (N_EDGES + N_NODES)
#define D_HID   64
#define N_CLS   40
#define SCAN_B  256
#define N_CHUNKS ((N_NODES + SCAN_B - 1) / SCAN_B)   // 196
#define NB      391                                   // dst buckets of 128 nodes
#define EPB     4096                                  // edges per pass-C block

typedef short bf16x8 __attribute__((ext_vector_type(8)));
typedef float f32x4  __attribute__((ext_vector_type(4)));
typedef float f32x2  __attribute__((ext_vector_type(2)));

// f32 -> fp8 e4m3 (gfx950 HW cvt; self-consistent round-trip with decoder)
__device__ __forceinline__ unsigned char f2fp8(float v) {
    return (unsigned char)(__builtin_amdgcn_cvt_pk_fp8_f32(v, v, 0, false) & 0xFF);
}

// manual f32 -> bf16 round-to-nearest-even
__device__ __forceinline__ unsigned short f2bf(float f) {
    unsigned u = __float_as_uint(f);
    u += 0x7FFFu + ((u >> 16) & 1);
    return (unsigned short)(u >> 16);
}
__device__ __forceinline__ unsigned pk_bf(float a, float b) {
    return (unsigned)f2bf(a) | ((unsigned)f2bf(b) << 16);
}

// ---- convert (+ inline dtype detect, + degree histogram) -------------------
__global__ void k_convert(const void* ei, int2* __restrict__ pairs,
                          int* __restrict__ deg) {
    __shared__ int s_is32;
    if (threadIdx.x == 0) s_is32 = 0;
    __syncthreads();
    const int* p32 = (const int*)ei;
    if (p32[2 * threadIdx.x + 1] != 0) atomicOr(&s_is32, 1);
    __syncthreads();
    int e = blockIdx.x * 256 + threadIdx.x;
    if (e >= N_EDGES) return;
    int s, d;
    if (s_is32) {
        s = p32[e]; d = p32[N_EDGES + e];
    } else {
        const long long* p64 = (const long long*)ei;
        s = (int)p64[e]; d = (int)p64[N_EDGES + e];
    }
    pairs[e] = make_int2(s, d);
    atomicAdd(&deg[d], 1);
}

// ---- CSR build: scan --------------------------------------------------------
__device__ __forceinline__ int block_scan_incl(int v, int* wsum) {
    int lane = threadIdx.x & 63, w = threadIdx.x >> 6;
    int s = v;
#pragma unroll
    for (int d = 1; d < 64; d <<= 1) {
        int t = __shfl_up(s, d, 64);
        if (lane >= d) s += t;
    }
    if (lane == 63) wsum[w] = s;
    __syncthreads();
    int add = 0;
    for (int ww = 0; ww < (threadIdx.x >> 6); ++ww) add += wsum[ww];
    return s + add;
}

__global__ void k_scan1(const int* __restrict__ deg, int* __restrict__ rowptr,
                        int* __restrict__ partials) {
    __shared__ int wsum[4];
    int i = blockIdx.x * SCAN_B + threadIdx.x;
    int v = (i < N_NODES) ? deg[i] + 1 : 0;      // +1 = self loop
    int s = block_scan_incl(v, wsum);
    if (i < N_NODES) rowptr[i] = s - v;          // block-local exclusive
    if (threadIdx.x == SCAN_B - 1) partials[blockIdx.x] = s;
}

__global__ void k_scan2(int* partials) {
    __shared__ int wsum[4];
    int i = threadIdx.x;
    int v = (i < N_CHUNKS) ? partials[i] : 0;
    int s = block_scan_incl(v, wsum);
    if (i < N_CHUNKS) partials[i] = s - v;       // exclusive
}

__global__ void k_scan3(const int* __restrict__ partials, int* __restrict__ rowptr) {
    int i = blockIdx.x * SCAN_B + threadIdx.x;
    if (i < N_NODES) rowptr[i] += partials[blockIdx.x];
    if (blockIdx.x == 0 && threadIdx.x == 0) rowptr[N_NODES] = E_TOT;
}

// bucket cursor init: pair-array base of bucket b is rowptr[128b] - 128b
__global__ void k_bucket_init(const int* __restrict__ rowptr, int* __restrict__ bcursor) {
    int b = threadIdx.x;
    if (b < NB) bcursor[b] = rowptr[b << 7] - (b << 7);
}

// ---- pass C: bucket-grouping scatter (LDS rank + one atomic per blk/bkt) ---
__global__ __launch_bounds__(256) void k_bucket_scatter(
        const int2* __restrict__ pairs_in, int* __restrict__ bcursor,
        int2* __restrict__ pairs_bkt) {
    __shared__ int counts[512];
    __shared__ int gbase[512];
    int t = threadIdx.x;
    counts[t] = 0; counts[t + 256] = 0;
    __syncthreads();
    int base = blockIdx.x * EPB;
    int nEdge = min(EPB, N_EDGES - base);
    int2 pr0, pr1, pr2, pr3, pr4, pr5, pr6, pr7, pr8, pr9, prA, prB, prC, prD, prE, prF;
    int rk[16], bk[16];
#define LOADI(i, pv) { int idx = t + (i) * 256;                        \
        if (idx < nEdge) { pv = pairs_in[base + idx];                   \
            bk[i] = pv.y >> 7; rk[i] = atomicAdd(&counts[bk[i]], 1); } }
    LOADI(0, pr0) LOADI(1, pr1) LOADI(2, pr2) LOADI(3, pr3)
    LOADI(4, pr4) LOADI(5, pr5) LOADI(6, pr6) LOADI(7, pr7)
    LOADI(8, pr8) LOADI(9, pr9) LOADI(10, prA) LOADI(11, prB)
    LOADI(12, prC) LOADI(13, prD) LOADI(14, prE) LOADI(15, prF)
#undef LOADI
    __syncthreads();
    if (counts[t])       gbase[t]       = atomicAdd(&bcursor[t], counts[t]);
    if (counts[t + 256]) gbase[t + 256] = atomicAdd(&bcursor[t + 256], counts[t + 256]);
    __syncthreads();
#define STOREI(i, pv) { int idx = t + (i) * 256;                        \
        if (idx < nEdge) pairs_bkt[gbase[bk[i]] + rk[i]] = pv; }
    STOREI(0, pr0) STOREI(1, pr1) STOREI(2, pr2) STOREI(3, pr3)
    STOREI(4, pr4) STOREI(5, pr5) STOREI(6, pr6) STOREI(7, pr7)
    STOREI(8, pr8) STOREI(9, pr9) STOREI(10, prA) STOREI(11, prB)
    STOREI(12, prC) STOREI(13, prD) STOREI(14, prE) STOREI(15, prF)
#undef STOREI
}

// ---- pass D: within-bucket placement (LDS cursors, L2-resident writes) -----
__global__ __launch_bounds__(256) void k_bucket_place(
        const int2* __restrict__ pairs_bkt, const int* __restrict__ rowptr,
        int* __restrict__ src_sorted) {
    __shared__ int cur[128];
    int b = blockIdx.x, t = threadIdx.x;
    int d0 = b << 7;
    int dEnd = min(d0 + 128, N_NODES);
    if (t < 128) {
        int d = d0 + t;
        if (d < dEnd) {
            int r = rowptr[d];
            src_sorted[r] = d;            // self loop (order within segment free)
            cur[t] = r + 1;
        }
    }
    __syncthreads();
    int pbase = rowptr[d0] - d0;
    int pend  = rowptr[dEnd] - dEnd;
    for (int idx = pbase + t; idx < pend; idx += 256) {
        int2 p = pairs_bkt[idx];
        int pos = atomicAdd(&cur[p.y - d0], 1);
        src_sorted[pos] = p.x;
    }
}

// ---- MFMA GEMM: Wh8(fp8) = x@W (+ alpha_s/alpha_t dots) --------------------
// Block 256 = 4 waves; tile 64x64; mfma_f32_16x16x32_bf16, f32 accumulate.
// A: lane l holds xb[l%16][(l/16)*8+j]; B: wt[col=l%16][k]; D: row=4*(l>>4)+reg,
// col=l&15 (m89-verified layouts). Epilogue quantizes to fp8 e4m3 (3.2MB array
// -> fits 4MiB per-XCD L2 for the aggr gather).
template<int K>
__global__ __launch_bounds__(256) void k_gemm_alpha(
        const float* __restrict__ x, const float* __restrict__ W,
        const float* __restrict__ aW,
        unsigned char* __restrict__ Wh8,
        float* __restrict__ alpha_s, float* __restrict__ alpha_t) {
    __shared__ unsigned short xb[64][K + 8];
    __shared__ unsigned short wt[64][K + 8];
    int tid = threadIdx.x;
    int rowBase = blockIdx.x * 64;

    // stage x -> xb bf16 (coalesced float4 global reads, packed uint LDS writes)
    {
        int rr = tid >> 2;                 // 0..63
        int kc = (tid & 3) * (K / 4);
        const float* xr = x + (size_t)min(rowBase + rr, N_NODES - 1) * K + kc;
        unsigned* dst = (unsigned*)&xb[rr][kc];
#pragma unroll
        for (int j = 0; j < K / 4; j += 8) {
            float4 v0 = *(const float4*)(xr + j);
            float4 v1 = *(const float4*)(xr + j + 4);
            dst[j / 2 + 0] = pk_bf(v0.x, v0.y);
            dst[j / 2 + 1] = pk_bf(v0.z, v0.w);
            dst[j / 2 + 2] = pk_bf(v1.x, v1.y);
            dst[j / 2 + 3] = pk_bf(v1.z, v1.w);
        }
    }
    // stage W -> wt bf16 transposed: wt[n][k] = W[k*64+n]
    for (int i = tid; i < K * 64; i += 256) {
        int k = i >> 6, n = i & 63;
        wt[n][k] = f2bf(W[i]);
    }
    __syncthreads();

    int w = tid >> 6, lane = tid & 63;
    int la = lane & 15, hi = lane >> 4;

    f32x4 acc[4];
#pragma unroll
    for (int c = 0; c < 4; ++c) acc[c] = (f32x4){0.f, 0.f, 0.f, 0.f};

#pragma unroll
    for (int t = 0; t < K / 32; ++t) {
        int k0 = t * 32 + hi * 8;
        bf16x8 af = *(const bf16x8*)&xb[w * 16 + la][k0];
#pragma unroll
        for (int c = 0; c < 4; ++c) {
            bf16x8 bfr = *(const bf16x8*)&wt[c * 16 + la][k0];
            acc[c] = __builtin_amdgcn_mfma_f32_16x16x32_bf16(af, bfr, acc[c], 0, 0, 0);
        }
    }

    // epilogue: lane holds D rows 4*hi+r of wave band, cols c*16+la.
    float as4[4], at4[4];
#pragma unroll
    for (int c = 0; c < 4; ++c) {
        as4[c] = aW[c * 16 + la];
        at4[c] = aW[64 + c * 16 + la];
    }
#pragma unroll
    for (int r = 0; r < 4; ++r) {
        int row = rowBase + w * 16 + hi * 4 + r;
        float ps = acc[0][r] * as4[0] + acc[1][r] * as4[1]
                 + acc[2][r] * as4[2] + acc[3][r] * as4[3];
        float pt = acc[0][r] * at4[0] + acc[1][r] * at4[1]
                 + acc[2][r] * at4[2] + acc[3][r] * at4[3];
#pragma unroll
        for (int o = 1; o < 16; o <<= 1) {
            ps += __shfl_xor(ps, o, 64);
            pt += __shfl_xor(pt, o, 64);
        }
        if (row < N_NODES) {
            unsigned char* wr = Wh8 + (size_t)row * 64;
#pragma unroll
            for (int c = 0; c < 4; ++c)
                wr[c * 16 + la] = f2fp8(acc[c][r]);
            if (la == 0) { alpha_s[row] = ps; alpha_t[row] = pt; }
        }
    }
}

// ---- slow path helper (deg > 64): chunked two-pass, scalar fp8 gather ------
__device__ void slow_node(int rs, int re, const int* __restrict__ src_sorted,
                          const float* __restrict__ alpha_s, float at,
                          const unsigned char* __restrict__ Wh8, int lane, int fl2,
                          float& z, float vm[8]) {
    float m = -INFINITY;
    for (int base = rs; base < re; base += 64) {
        int idx = base + lane;
        float sim = -INFINITY;
        if (idx < re) {
            int sv = src_sorted[idx];
            float t = alpha_s[sv] + at;
            sim = t > 0.f ? t : 0.2f * t;
        }
#pragma unroll
        for (int o = 32; o; o >>= 1) sim = fmaxf(sim, __shfl_xor(sim, o, 64));
        m = fmaxf(m, sim);
    }
    z = 0.f;
    float vsc = -INFINITY;
    for (int base = rs; base < re; base += 64) {
        int idx = base + lane;
        int cnt = min(64, re - base);
        int svv = 0;
        float ev = 0.f;
        if (idx < re) {
            svv = src_sorted[idx];
            float t = alpha_s[svv] + at;
            t = t > 0.f ? t : 0.2f * t;
            ev = __expf(t - m);
        }
        float sz = ev;
#pragma unroll
        for (int o = 32; o; o >>= 1) sz += __shfl_xor(sz, o, 64);
        z += sz;
        for (int j = 0; j < cnt; ++j) {
            int sj = __shfl(svv, j, 64);
            float ej = __shfl(ev, j, 64);
            unsigned b = Wh8[(size_t)sj * 64 + lane];
            f32x2 p = __builtin_amdgcn_cvt_pk_f32_fp8(b, false);
            vsc = fmaxf(vsc, ej * p.x);
        }
    }
#pragma unroll
    for (int q = 0; q < 8; ++q) vm[q] = __shfl(vsc, fl2 * 8 + q, 64);
}

// ---- per-dst-node fused: attention softmax + scatter-max aggregation -------
// TWO nodes per wave (A,B); 8-lane groups, 8B/lane fp8 loads (8 edges/round/
// node), HW fp8->f32 cvt, f32 max accumulate. Wh8 = 3.2MB -> per-XCD L2-fit.
template<int HEAD>
__global__ void k_node_aggr(const int* __restrict__ rowptr, const int* __restrict__ src_sorted,
                            const float* __restrict__ alpha_s, const float* __restrict__ alpha_t,
                            const float* __restrict__ ab, const unsigned char* __restrict__ Wh8,
                            const float* __restrict__ bias,
                            const float* __restrict__ Wo, const float* __restrict__ bo,
                            float* __restrict__ outp) {
    __shared__ float sWo[HEAD ? 64 * N_CLS : 1];
    __shared__ float sh[HEAD ? 8 * 64 : 1];
    int lane = threadIdx.x, w = threadIdx.y;
    if (HEAD) {
        int tid = w * 64 + lane;
        for (int i = tid; i < 64 * N_CLS; i += 256) sWo[i] = Wo[i];
    }
    int dA = blockIdx.x * 8 + w * 2;       // grid exact: 6250*8 == N_NODES
    int dB = dA + 1;
    int rsA = rowptr[dA], reA = rowptr[dA + 1];
    int rsB = rowptr[dB], reB = rowptr[dB + 1];
    int degA = reA - rsA, degB = reB - rsB;
    float abv = ab[0];
    float atA = alpha_t[dA] + abv;
    float atB = alpha_t[dB] + abv;
    int g2 = lane >> 3, fl2 = lane & 7;
    const unsigned char* whb = Wh8;

    float zA, zB;
    float vmA[8], vmB[8];

    if (degA <= 64 && degB <= 64) {
        // --- dual fast path ---
        int svA = src_sorted[rsA + min(lane, degA - 1)];
        int svB = src_sorted[rsB + min(lane, degB - 1)];
        float tA = alpha_s[svA] + atA; tA = tA > 0.f ? tA : 0.2f * tA;
        float tB = alpha_s[svB] + atB; tB = tB > 0.f ? tB : 0.2f * tB;
        float evA = __expf(tA);            // no max-subtract: |t| is O(1)
        float evB = __expf(tB);
        float zzA = (lane < degA) ? evA : 0.f;
        float zzB = (lane < degB) ? evB : 0.f;
#pragma unroll
        for (int o = 32; o; o >>= 1) {
            zzA += __shfl_xor(zzA, o, 64);
            zzB += __shfl_xor(zzB, o, 64);
        }
        zA = zzA; zB = zzB;
        int ofsA = svA * 64, ofsB = svB * 64;     // byte offsets of fp8 rows

#pragma unroll
        for (int q = 0; q < 8; ++q) { vmA[q] = -INFINITY; vmB[q] = -INFINITY; }
#define ROUND(ev, ofs, deg, vm, r) { \
        int j = (r) * 8 + g2; j = j < (deg) ? j : (deg) - 1;              \
        float ej = __shfl((ev), j, 64);                                   \
        int ro = __shfl((ofs), j, 64);                                    \
        uint2 hv = *(const uint2*)(whb + ro + fl2 * 8);                   \
        f32x2 p0 = __builtin_amdgcn_cvt_pk_f32_fp8(hv.x, false);          \
        f32x2 p1 = __builtin_amdgcn_cvt_pk_f32_fp8(hv.x, true);           \
        f32x2 p2 = __builtin_amdgcn_cvt_pk_f32_fp8(hv.y, false);          \
        f32x2 p3 = __builtin_amdgcn_cvt_pk_f32_fp8(hv.y, true);           \
        vm[0] = fmaxf(vm[0], ej * p0.x); vm[1] = fmaxf(vm[1], ej * p0.y); \
        vm[2] = fmaxf(vm[2], ej * p1.x); vm[3] = fmaxf(vm[3], ej * p1.y); \
        vm[4] = fmaxf(vm[4], ej * p2.x); vm[5] = fmaxf(vm[5], ej * p2.y); \
        vm[6] = fmaxf(vm[6], ej * p3.x); vm[7] = fmaxf(vm[7], ej * p3.y); }
#define RA(r) ROUND(evA, ofsA, degA, vmA, r)
#define RB(r) ROUND(evB, ofsB, degB, vmB, r)

        RA(0) RB(0) RA(1) RB(1)
        if (degA > 16) { RA(2) RA(3) }
        if (degB > 16) { RB(2) RB(3) }
        if (degA > 32) { RA(4) RA(5) RA(6) RA(7) }
        if (degB > 32) { RB(4) RB(5) RB(6) RB(7) }
#undef RA
#undef RB
#undef ROUND
        // combine across the 8 groups (lane bits 3,4,5)
#pragma unroll
        for (int o = 8; o <= 32; o <<= 1) {
#pragma unroll
            for (int q = 0; q < 8; ++q) {
                vmA[q] = fmaxf(vmA[q], __shfl_xor(vmA[q], o, 64));
                vmB[q] = fmaxf(vmB[q], __shfl_xor(vmB[q], o, 64));
            }
        }
    } else {
        slow_node(rsA, reA, src_sorted, alpha_s, atA, Wh8, lane, fl2, zA, vmA);
        slow_node(rsB, reB, src_sorted, alpha_s, atB, Wh8, lane, fl2, zB, vmB);
    }

    // epilogue per node: h = vmax/z + bias, relu.
    float4 b0 = *(const float4*)(bias + fl2 * 8);
    float4 b1 = *(const float4*)(bias + fl2 * 8 + 4);
    float bias8[8] = { b0.x, b0.y, b0.z, b0.w, b1.x, b1.y, b1.z, b1.w };
    float rzA = 1.0f / zA, rzB = 1.0f / zB;
    float h8A[8], h8B[8];
#pragma unroll
    for (int q = 0; q < 8; ++q) {
        h8A[q] = fmaxf(vmA[q] * rzA + bias8[q], 0.f);
        h8B[q] = fmaxf(vmB[q] * rzB + bias8[q], 0.f);
    }

    if (!HEAD) {
        if (g2 == 0) {
            float* op = outp + (size_t)dA * 64 + fl2 * 8;
            *(float4*)op = make_float4(h8A[0], h8A[1], h8A[2], h8A[3]);
            *(float4*)(op + 4) = make_float4(h8A[4], h8A[5], h8A[6], h8A[7]);
        } else if (g2 == 1) {
            float* op = outp + (size_t)dB * 64 + fl2 * 8;
            *(float4*)op = make_float4(h8B[0], h8B[1], h8B[2], h8B[3]);
            *(float4*)(op + 4) = make_float4(h8B[4], h8B[5], h8B[6], h8B[7]);
        }
    } else {
        if (g2 == 0) {
            float* sp = sh + (2 * w) * 64 + fl2 * 8;
            *(float4*)sp = make_float4(h8A[0], h8A[1], h8A[2], h8A[3]);
            *(float4*)(sp + 4) = make_float4(h8A[4], h8A[5], h8A[6], h8A[7]);
        } else if (g2 == 1) {
            float* sp = sh + (2 * w + 1) * 64 + fl2 * 8;
            *(float4*)sp = make_float4(h8B[0], h8B[1], h8B[2], h8B[3]);
            *(float4*)(sp + 4) = make_float4(h8B[4], h8B[5], h8B[6], h8B[7]);
        }
        __syncthreads();
#pragma unroll
        for (int n = 0; n < 2; ++n) {
            int dd = dA + n;
            const float* hrow = sh + (2 * w + n) * 64;
            float logit = -INFINITY;
            if (lane < N_CLS) {
                float acc = bo[lane];
#pragma unroll
                for (int k = 0; k < 64; ++k)
                    acc = fmaf(hrow[k], sWo[k * N_CLS + lane], acc);
                logit = acc;
            }
            float mx = logit;
#pragma unroll
            for (int o = 32; o; o >>= 1) mx = fmaxf(mx, __shfl_xor(mx, o, 64));
            float ex = (lane < N_CLS) ? __expf(logit - mx) : 0.f;
            float sm = ex;
#pragma unroll
            for (int o = 32; o; o >>= 1) sm += __shfl_xor(sm, o, 64);
            float lse = mx + __logf(sm);
            if (lane < N_CLS) outp[(size_t)dd * N_CLS + lane] = logit - lse;
        }
    }
}

extern "C" void kernel_launch(void* const* d_in, const int* in_sizes, int n_in,
                              void* d_out, int out_size, void* d_ws, size_t ws_size,
                              hipStream_t stream) {
    const float* x   = (const float*)d_in[0];
    const void*  ei  = d_in[1];
    const float* W1  = (const float*)d_in[2];
    const float* aW1 = (const float*)d_in[3];
    const float* ab1 = (const float*)d_in[4];
    const float* b1  = (const float*)d_in[5];
    const float* W2  = (const float*)d_in[6];
    const float* aW2 = (const float*)d_in[7];
    const float* ab2 = (const float*)d_in[8];
    const float* b2  = (const float*)d_in[9];
    const float* Wo  = (const float*)d_in[10];
    const float* bo  = (const float*)d_in[11];
    float* out = (float*)d_out;

    char* ws = (char*)d_ws;
    size_t off = 0;
    auto alloc = [&](size_t bytes) {
        void* p = ws + off;
        off += (bytes + 255) & ~(size_t)255;
        return p;
    };
    int2*  pairs      = (int2*)alloc((size_t)N_EDGES * 8);
    int2*  pairs_bkt  = (int2*)alloc((size_t)N_EDGES * 8);
    int*   deg        = (int*)alloc((size_t)N_NODES * 4);
    int*   rowptr     = (int*)alloc((size_t)(N_NODES + 1) * 4);
    int*   bcursor    = (int*)alloc((size_t)512 * 4);
    int*   partials   = (int*)alloc((size_t)SCAN_B * 4);
    int*   src_sorted = (int*)alloc((size_t)E_TOT * 4);
    unsigned char* Wh8 = (unsigned char*)alloc((size_t)N_NODES * 64);
    float* h_mid      = (float*)alloc((size_t)N_NODES * 64 * 4);
    float* alpha_s    = (float*)alloc((size_t)N_NODES * 4);
    float* alpha_t    = (float*)alloc((size_t)N_NODES * 4);

    const int B = 256;
    int gEdgeE = (N_EDGES + B - 1) / B;
    int gPassC = (N_EDGES + EPB - 1) / EPB;   // 196
    dim3 blk2(64, 4);
    int gRow  = N_NODES / 8;            // 6250, exact (2 nodes/wave)
    int gGemm = (N_NODES + 63) / 64;    // 782

    // ---- CSR build (two-level counting sort)
    hipMemsetAsync(deg, 0, (size_t)N_NODES * 4, stream);
    k_convert<<<gEdgeE, B, 0, stream>>>(ei, pairs, deg);
    k_scan1<<<N_CHUNKS, SCAN_B, 0, stream>>>(deg, rowptr, partials);
    k_scan2<<<1, SCAN_B, 0, stream>>>(partials);
    k_scan3<<<N_CHUNKS, SCAN_B, 0, stream>>>(partials, rowptr);
    k_bucket_init<<<1, 512, 0, stream>>>(rowptr, bcursor);
    k_bucket_scatter<<<gPassC, B, 0, stream>>>(pairs, bcursor, pairs_bkt);
    k_bucket_place<<<NB, B, 0, stream>>>(pairs_bkt, rowptr, src_sorted);

    // ---- layer 1
    k_gemm_alpha<128><<<gGemm, 256, 0, stream>>>(x, W1, aW1, Wh8, alpha_s, alpha_t);
    k_node_aggr<0><<<gRow, blk2, 0, stream>>>(rowptr, src_sorted, alpha_s, alpha_t,
                                              ab1, Wh8, b1, nullptr, nullptr, h_mid);

    // ---- layer 2 (+ fused output head)
    k_gemm_alpha<64><<<gGemm, 256, 0, stream>>>(h_mid, W2, aW2, Wh8, alpha_s, alpha_t);
    k_node_aggr<1><<<gRow, blk2, 0, stream>>>(rowptr, src_sorted, alpha_s, alpha_t,
                                              ab2, Wh8, b2, Wo, bo, out);
}